// Round 9
// baseline (105.822 us; speedup 1.0000x reference)
//
#include <hip/hip_runtime.h>
#include <math.h>

#define EPS_F 1e-6f
#define S_DIM 768
#define W_DIM 32
#define H_DIM 12
#define NK 33   // intervals = W_DIM + 1

// ws float layout:
//   [0 .. 32)                      sorted hinge values (ascending)
//   [32 + h*2*NK + 2k]  = A_k(h)   (slope)
//   [32 + h*2*NK + 2k+1]= B_k(h)   (intercept, includes b_out[h])

// ---------------- setup: build sorted hinges + per-(h,k) PWL tables ----------
__global__ __launch_bounds__(512) void cope_setup_kernel(
    const float* __restrict__ W_in, const float* __restrict__ b_in,
    const float* __restrict__ W_out, const float* __restrict__ b_out,
    float* __restrict__ ws)
{
    __shared__ float th[W_DIM];
    __shared__ int   rk[W_DIM];
    const int t = threadIdx.x;

    if (t < W_DIM) {
        float w1 = W_in[t], b = b_in[t];
        th[t] = (w1 != 0.0f) ? (-b / w1) : __builtin_inff();
    }
    __syncthreads();

    if (t < W_DIM) {
        float mine = th[t];
        int r = 0;
        for (int v = 0; v < W_DIM; v++) {
            float o = th[v];
            if (o < mine || (o == mine && v < t)) r++;
        }
        rk[t] = r;          // sorted rank of hinge t (ties broken by index)
        ws[r] = mine;       // sorted hinge array
    }
    __syncthreads();

    if (t < H_DIM * NK) {
        int h = t / NK, k = t % NK;   // interval k: exactly k hinges < dist
        float A = 0.0f, B = b_out[h];
        for (int w = 0; w < W_DIM; w++) {
            float w1 = W_in[w], bv = b_in[w], ov = W_out[h * W_DIM + w];
            bool active = (w1 > 0.0f) ? (k > rk[w])
                        : (w1 < 0.0f) ? (k <= rk[w])
                        : (bv > 0.0f);
            if (active) { A += w1 * ov; B += bv * ov; }
        }
        ws[W_DIM + h * 2 * NK + 2 * k]     = A;
        ws[W_DIM + h * 2 * NK + 2 * k + 1] = B;
    }
}

// ---------------- main: 2 rows per wave, shallow-LDS PWL evaluation ---------
__global__ __launch_bounds__(256) void cope_fire_kernel(
    const float* __restrict__ attn,   // (H*S, S)
    const float* __restrict__ c_p,
    const float* __restrict__ Lm_p,
    const float* __restrict__ iL_p,
    const float* __restrict__ ws,
    float* __restrict__ out)
{
    const int t    = threadIdx.x;
    const int lane = t & 63;
    const int wave = t >> 6;
    const int row0 = blockIdx.x * 8 + wave;       // wave's first row
    const int row1 = row0 + 4;                    // wave's second row
    const int h    = blockIdx.x / (S_DIM / 8);    // block-uniform (96 blk/h)

    // hinge groups of 4, PADDED to 8-float stride (32B) -> b128 reads land on
    // distinct bank quads (2 addr/quad = free 2-way, vs 4-way unpadded)
    __shared__ float  sh4[64];      // group b at [8b .. 8b+4)
    __shared__ float2 sAB[NK];

    if (t < W_DIM) sh4[(t >> 2) * 8 + (t & 3)] = ws[t];
    if (t < NK) {
        const float* p = ws + W_DIM + h * 2 * NK + 2 * t;
        sAB[t] = make_float2(p[0], p[1]);
    }

    // ---- issue BOTH rows' global loads first (max MLP per wave) ----
    const float* r0p = attn + (size_t)row0 * S_DIM + lane * 12;
    const float* r1p = attn + (size_t)row1 * S_DIM + lane * 12;
    float4 a0 = *(const float4*)(r0p);
    float4 a1 = *(const float4*)(r0p + 4);
    float4 a2 = *(const float4*)(r0p + 8);
    float4 b0 = *(const float4*)(r1p);
    float4 b1 = *(const float4*)(r1p + 4);
    float4 b2 = *(const float4*)(r1p + 8);

    // SGPR-resident tree comparators (uniform constant-index loads)
    const float h15 = ws[15];
    const float h7  = ws[7],  h23 = ws[23];
    const float h3  = ws[3],  h11 = ws[11], h19 = ws[19], h27 = ws[27];
    const float c   = c_p[0];
    const float thr = fabsf(Lm_p[0] * iL_p[0]);

    float g[2][12] = { { a0.x, a0.y, a0.z, a0.w, a1.x, a1.y, a1.z, a1.w,
                         a2.x, a2.y, a2.z, a2.w },
                       { b0.x, b0.y, b0.z, b0.w, b1.x, b1.y, b1.z, b1.w,
                         b2.x, b2.y, b2.z, b2.w } };
#pragma unroll
    for (int r = 0; r < 2; r++)
#pragma unroll
        for (int i = 0; i < 12; i++)
            g[r][i] = __builtin_amdgcn_rcpf(1.0f + __expf(-g[r][i]));

    // lane totals + two independent inclusive wave scans (interleaved chains)
    float T0 = 0.0f, T1 = 0.0f;
#pragma unroll
    for (int i = 0; i < 12; i++) { T0 += g[0][i]; T1 += g[1][i]; }
    float P0 = T0, P1 = T1;
#pragma unroll
    for (int d = 1; d < 64; d <<= 1) {
        float y0 = __shfl_up(P0, d, 64);
        float y1 = __shfl_up(P1, d, 64);
        if (lane >= d) { P0 += y0; P1 += y1; }
    }
    const float tot0  = __shfl(P0, 63, 64);
    const float tot1  = __shfl(P1, 63, 64);
    const float base0 = tot0 - P0 + T0;   // suffix sum at lane's first element
    const float base1 = tot1 - P1 + T1;

    const float id0 = __builtin_amdgcn_rcpf(
        __logf(fabsf(c * fminf(tot0, thr)) + 1.0f) + EPS_F);
    const float id1 = __builtin_amdgcn_rcpf(
        __logf(fabsf(c * fminf(tot1, thr)) + 1.0f) + EPS_F);

    // dist for all elements, both rows (2 independent chains)
    float e0 = 0.0f, e1 = 0.0f;
#pragma unroll
    for (int i = 0; i < 12; i++) {
        float p0 = base0 - e0; e0 += g[0][i];
        float p1 = base1 - e1; e1 += g[1][i];
        g[0][i] = __logf(fabsf(c * p0) + 1.0f) * id0;
        g[1][i] = __logf(fabsf(c * p1) + 1.0f) * id1;
    }

    __syncthreads();   // tables ready

    // ---- per-element: 3 SGPR-tree levels -> 1 padded b128 + count -> sAB ----
    float* o0 = out + (size_t)row0 * S_DIM + lane * 12;
    float* o1 = out + (size_t)row1 * S_DIM + lane * 12;
#pragma unroll
    for (int r = 0; r < 2; r++) {
        float o[12];
#pragma unroll
        for (int i = 0; i < 12; i++) {
            float d = g[r][i];
            bool m1 = (h15 < d);
            float l2 = m1 ? h23 : h7;
            bool m2 = (l2 < d);
            float l3 = m2 ? (m1 ? h27 : h11) : (m1 ? h19 : h3);
            bool m3 = (l3 < d);
            int base = (m1 ? 16 : 0) + (m2 ? 8 : 0) + (m3 ? 4 : 0);

            float4 hv = *(const float4*)(&sh4[base * 2]);  // padded group
            int k = base + (hv.x < d) + (hv.y < d) + (hv.z < d) + (hv.w < d);

            float2 ab = sAB[k];
            o[i] = fmaf(d, ab.x, ab.y);
        }
        float* op = (r == 0) ? o0 : o1;
        *(float4*)(op)     = make_float4(o[0], o[1], o[2],  o[3]);
        *(float4*)(op + 4) = make_float4(o[4], o[5], o[6],  o[7]);
        *(float4*)(op + 8) = make_float4(o[8], o[9], o[10], o[11]);
    }
}

extern "C" void kernel_launch(void* const* d_in, const int* in_sizes, int n_in,
                              void* d_out, int out_size, void* d_ws, size_t ws_size,
                              hipStream_t stream) {
    const float* attn  = (const float*)d_in[0];
    const float* W_in  = (const float*)d_in[1];
    const float* b_in  = (const float*)d_in[2];
    const float* W_out = (const float*)d_in[3];
    const float* b_out = (const float*)d_in[4];
    const float* c_p   = (const float*)d_in[5];
    const float* Lm_p  = (const float*)d_in[6];
    const float* iL_p  = (const float*)d_in[7];
    float* out = (float*)d_out;
    float* ws  = (float*)d_ws;

    cope_setup_kernel<<<1, 512, 0, stream>>>(W_in, b_in, W_out, b_out, ws);

    const int blocks = H_DIM * S_DIM / 8;      // 1152 blocks, 8 rows each
    cope_fire_kernel<<<blocks, 256, 0, stream>>>(
        attn, c_p, Lm_p, iL_p, ws, out);
}